// Round 3
// baseline (486.628 us; speedup 1.0000x reference)
//
#include <hip/hip_runtime.h>
#include <hip/hip_bf16.h>

// Net_22625887715641: fused conv-feats + channel-normalize + 32x32 normalized
// cross-correlation (23x23 shifts, 362x362 templates).
//
// R3 vs R2 (corr 251us @ MfmaUtil 27.6%, feat ~170us):
//  - corr: 512-thr blocks, wave=(Mt-triple, N-half), acc 72 AGPR -> 2 waves/SIMD
//    (R2: 144 AGPR + 128 VGPR ~ 1 wave/SIMD on unified file). Grid 256 = 1/CU.
//  - B in LDS as 8 shifted copies (s=dx&7), staged with funnel-shift
//    ds_write_b128, read as ONE aligned ds_read_b128 per fragment (R2: 4x
//    unaligned b32 + 4-way conflicts). Copy stagger 208s+4(s>>1) -> <=2-way.
//  - feat: 4px/thread j-blocked, float2 window loads, 1-wave blocks grid 1152.

typedef unsigned short ushort_t;
typedef unsigned int uint_t;
typedef __attribute__((ext_vector_type(8))) short bf16x8;    // 8 bf16 = 4 VGPRs
typedef __attribute__((ext_vector_type(4))) float f32x4;
typedef __attribute__((ext_vector_type(4))) uint_t uint4_t;
typedef __attribute__((ext_vector_type(4))) ushort_t ushortx4;

#define EPSF 2.2204460492503131e-16f
#define X1_N (32*384*384)
#define X2_N (32*32*23*23)

// filtb: [372 rows][48 xb][32 o][8 xi] bf16; row = yf+5 (yf=0..361 at rows 5..366)
#define FILTB_ELEMS (372*48*32*8)
// prevb: [32 c][392 rows][408 x] bf16; data rows 0..383, cols 0..383; zeros else
#define PREVB_ELEMS (32*392*408)
#define WS_BYTES ((size_t)(FILTB_ELEMS + PREVB_ELEMS)*2)

#define YMAX 367            // y-steps 0..366
#define NSTEP_CHUNK 24
#define NCHUNK 16           // 16*24 = 384 >= 367
#define INV_AREA (1.0f/131044.0f)

// sB (u32 words): [rowi 8][copy 8]; copy s base = 208*s + 4*(s>>1); row stride 1676
#define SB_RS 1676
#define SB_WORDS (8*SB_RS)   // 13408 words = 53632 B

// ---------------------------------------------------------------------------
// Stage 1: conv (temp 3x11x11 + notemp 11x11), relu, /2 on temp, channel
// normalize. mode 0: x -> x1 + filtb pack. mode 1: xprev -> prevb.
// 4 px per thread (j-blocked), sliding window, float2 loads (8B-aligned:
// row offset even, j0 = 4*qx even). Filter addresses wave-uniform -> s_load.
// ---------------------------------------------------------------------------
__global__ __launch_bounds__(64) void feat_kernel(
    const float* __restrict__ xcur, const float* __restrict__ xprev,
    const float* __restrict__ ft,   const float* __restrict__ fn,
    float* __restrict__ out_x1, ushort_t* __restrict__ filtb,
    ushort_t* __restrict__ prevb)
{
  const int tx = threadIdx.x & 15, ty = threadIdx.x >> 4;
  const int qx = blockIdx.x * 16 + tx;   // 0..95
  const int j0 = qx * 4;                 // 0..380
  const int i = blockIdx.y * 4 + ty;     // 0..383
  const int mode = blockIdx.z;
  const float* xin = mode ? xprev : xcur;

  float acc[4][32];                      // [jj][ch]
#pragma unroll
  for (int jj = 0; jj < 4; ++jj)
#pragma unroll
    for (int c = 0; c < 32; ++c) acc[jj][c] = 0.f;

  for (int t = 0; t < 3; ++t) {
    for (int a = 0; a < 11; ++a) {
      const float2* rp = (const float2*)(xin + ((size_t)t * 394 + i + a) * 394 + j0);
      float wv[14];
#pragma unroll
      for (int k = 0; k < 7; ++k) {
        const float2 v = rp[k];
        wv[2 * k] = v.x; wv[2 * k + 1] = v.y;
      }
#pragma unroll
      for (int b = 0; b < 11; ++b) {
#pragma unroll
        for (int ch = 0; ch < 16; ++ch) {
          const float f = ft[(ch * 3 + t) * 121 + a * 11 + b];
#pragma unroll
          for (int jj = 0; jj < 4; ++jj)
            acc[jj][ch] = fmaf(wv[b + jj], f, acc[jj][ch]);
        }
        if (t == 2) {
#pragma unroll
          for (int ch = 0; ch < 16; ++ch) {
            const float f = fn[ch * 121 + a * 11 + b];
#pragma unroll
            for (int jj = 0; jj < 4; ++jj)
              acc[jj][16 + ch] = fmaf(wv[b + jj], f, acc[jj][16 + ch]);
          }
        }
      }
    }
  }

  float inv[4];
#pragma unroll
  for (int jj = 0; jj < 4; ++jj) {
    float s = EPSF;
#pragma unroll
    for (int c = 0; c < 32; ++c) {
      float v = fmaxf(acc[jj][c], 0.f);
      if (c < 16) v *= 0.5f;             // temp channels: relu(conv)/2
      acc[jj][c] = v;
      s += v;
    }
    inv[jj] = 1.f / s;
  }

  if (mode == 0) {
    __hip_bfloat16* fb = (__hip_bfloat16*)filtb;
    const bool irow = (i >= 11) && (i <= 372);
    const int rowr = i - 6;
#pragma unroll
    for (int c = 0; c < 32; ++c) {
      float4 o4;
      o4.x = acc[0][c] * inv[0]; o4.y = acc[1][c] * inv[1];
      o4.z = acc[2][c] * inv[2]; o4.w = acc[3][c] * inv[3];
      *(float4*)(out_x1 + c * (384 * 384) + i * 384 + j0) = o4;
      if (irow) {
        const float vv[4] = {o4.x, o4.y, o4.z, o4.w};
#pragma unroll
        for (int jj = 0; jj < 4; ++jj) {
          const int j = j0 + jj;
          if (j >= 11 && j <= 372) {
            const int xc = j - 11;
            fb[((rowr * 48 + (xc >> 3)) * 32 + c) * 8 + (xc & 7)] = __float2bfloat16(vv[jj]);
          }
        }
      }
    }
  } else {
#pragma unroll
    for (int c = 0; c < 32; ++c) {
      ushortx4 o4;
      o4.x = __builtin_bit_cast(ushort_t, __float2bfloat16(acc[0][c] * inv[0]));
      o4.y = __builtin_bit_cast(ushort_t, __float2bfloat16(acc[1][c] * inv[1]));
      o4.z = __builtin_bit_cast(ushort_t, __float2bfloat16(acc[2][c] * inv[2]));
      o4.w = __builtin_bit_cast(ushort_t, __float2bfloat16(acc[3][c] * inv[3]));
      *(ushortx4*)(prevb + (size_t)(c * 392 + i) * 408 + j0) = o4;
    }
  }
}

// ---------------------------------------------------------------------------
// Stage 2: correlation via 16x16x32 bf16 MFMA.
//   out[o,c,dy,dx] = sum_{y,x} filt[o][y-dy_a][x] * prev[c][y+6*dy_b][x+dx]
//   M=(dy_a,o)=192, N=(cc,dyb,dx)=184(pad 192), K=(y outer, x 0..383)
// 512 thr = 8 waves; wave w: Mt = 3*(w&3)+m3, nt = 6*(w>>2)+ntl. acc 3x6 f32x4.
// B: 8 shifted copies in LDS, fragment = one aligned ds_read_b128.
// ---------------------------------------------------------------------------
__global__ __launch_bounds__(512, 2) void corr_kernel(
    const ushort_t* __restrict__ filtb, const ushort_t* __restrict__ prevb,
    float* __restrict__ x2)
{
  __shared__ uint_t sB[SB_WORDS];        // 53632 B

  const int tid = threadIdx.x;
  const int lane = tid & 63;
  const int w = tid >> 6;                // 0..7
  const int g = w & 3;                   // Mt group (Mt = 3g..3g+2)
  const int nh = w >> 2;                 // N half
  const int h = lane >> 4;               // quad 0..3
  const int nl = lane & 15;

  const int pair = blockIdx.x >> 4;      // 0..15
  const int chunk = blockIdx.x & 15;     // 0..15; %8 == XCD
  const int c0 = pair * 2;
  const int y0 = chunk * NSTEP_CHUNK;
  const int y1 = (y0 + NSTEP_CHUNK < YMAX) ? (y0 + NSTEP_CHUNK) : YMAX;

  // Per-lane B-fragment word offsets (16*Kt added at use). All 16B-aligned.
  int boffW[6];
#pragma unroll
  for (int ntl = 0; ntl < 6; ++ntl) {
    int n = (nh * 6 + ntl) * 16 + nl;
    if (n >= 184) n = 183;               // pad lanes: valid data, never stored
    const int cc = n / 92;
    const int rem = n - 92 * cc;
    const int dyb = rem / 23;
    const int dx = rem - 23 * dyb;
    const int s = dx & 7, a = dx >> 3;
    boffW[ntl] = (cc * 4 + dyb) * SB_RS + s * 208 + 4 * (s >> 1) + 4 * a + 4 * h;
  }

  // Staging role: task = tid (<400 active): row sr = task/50, block sc = task%50
  const int sr = tid / 50;               // 0..7 (cc=sr>>2, dyb=sr&3) for tid<400
  const int sc = tid - 50 * sr;          // 0..49
  const bool st_act = (tid < 400);
  const uint_t* srcrow = (const uint_t*)(prevb +
      ((size_t)((c0 + (sr >> 2)) * 392 + 6 * (sr & 3))) * 408);  // + y*204
  uint_t* dstb = sB + sr * SB_RS + 4 * sc;

  f32x4 acc[3][6];
  const f32x4 zero = {0.f, 0.f, 0.f, 0.f};
#pragma unroll
  for (int a = 0; a < 3; ++a)
#pragma unroll
    for (int b = 0; b < 6; ++b) acc[a][b] = zero;

  uint_t st[8];
  if (st_act) {
    const uint4_t* p4 = (const uint4_t*)(srcrow + (size_t)y0 * 204 + 4 * sc);
    const uint4_t lo = p4[0], hi = p4[1];
    st[0]=lo.x; st[1]=lo.y; st[2]=lo.z; st[3]=lo.w;
    st[4]=hi.x; st[5]=hi.y; st[6]=hi.z; st[7]=hi.w;
  }

  for (int y = y0; y < y1; ++y) {
    __syncthreads();                     // prior compute done reading sB
    if (st_act) {
#pragma unroll
      for (int s = 0; s < 8; ++s) {
        const int p = s >> 1;
        uint4_t v;
        if ((s & 1) == 0) {
          v = uint4_t{st[p], st[p + 1], st[p + 2], st[p + 3]};
        } else {
          v = uint4_t{(st[p] >> 16)     | (st[p + 1] << 16),
                      (st[p + 1] >> 16) | (st[p + 2] << 16),
                      (st[p + 2] >> 16) | (st[p + 3] << 16),
                      (st[p + 3] >> 16) | (st[p + 4] << 16)};
        }
        *(uint4_t*)(dstb + s * 208 + 4 * (s >> 1)) = v;
      }
    }
    __syncthreads();                     // staging visible

    if (st_act && (y + 1 < y1)) {        // prefetch next-y source rows
      const uint4_t* p4 = (const uint4_t*)(srcrow + (size_t)(y + 1) * 204 + 4 * sc);
      const uint4_t lo = p4[0], hi = p4[1];
      st[0]=lo.x; st[1]=lo.y; st[2]=lo.z; st[3]=lo.w;
      st[4]=hi.x; st[5]=hi.y; st[6]=hi.z; st[7]=hi.w;
    }

#pragma unroll
    for (int Kt = 0; Kt < 12; ++Kt) {
      bf16x8 Af[3];
#pragma unroll
      for (int m3 = 0; m3 < 3; ++m3) {
        const int Mt = 3 * g + m3;
        const int row = y - (Mt >> 1) + 5;           // in [0,371]
        const int o = ((Mt & 1) << 4) + nl;
        Af[m3] = *(const bf16x8*)(filtb + (((size_t)(row * 48 + Kt * 4 + h) * 32 + o) << 3));
      }
#pragma unroll
      for (int ntl = 0; ntl < 6; ++ntl) {
        const bf16x8 Bf = *(const bf16x8*)(sB + boffW[ntl] + (Kt << 4));
#pragma unroll
        for (int m3 = 0; m3 < 3; ++m3)
          acc[m3][ntl] = __builtin_amdgcn_mfma_f32_16x16x32_bf16(Af[m3], Bf, acc[m3][ntl], 0, 0, 0);
      }
    }
  }

  // Epilogue: scale partials, atomically accumulate into x2[o][c][dy][dx].
#pragma unroll
  for (int ntl = 0; ntl < 6; ++ntl) {
    const int n = (nh * 6 + ntl) * 16 + nl;
    if (n < 184) {
      const int cc = n / 92;
      const int rem = n - 92 * cc;
      const int dyb = rem / 23;
      const int dx = rem - 23 * dyb;
#pragma unroll
      for (int m3 = 0; m3 < 3; ++m3) {
        const int Mtb = (3 * g + m3) * 16;
#pragma unroll
        for (int r = 0; r < 4; ++r) {
          const int m = Mtb + h * 4 + r;   // C/D: row=(lane>>4)*4+reg, col=lane&15
          const int o = m & 31;
          const int dy = (m >> 5) + 6 * dyb;
          if (dy <= 22)
            atomicAdd(&x2[((o * 32 + (c0 + cc)) * 23 + dy) * 23 + dx],
                      acc[m3][ntl][r] * INV_AREA);
        }
      }
    }
  }
}

// ---------------------------------------------------------------------------
extern "C" void kernel_launch(void* const* d_in, const int* in_sizes, int n_in,
                              void* d_out, int out_size, void* d_ws, size_t ws_size,
                              hipStream_t stream)
{
  const float* x     = (const float*)d_in[0];   // [3][394][394]
  const float* xprev = (const float*)d_in[1];
  const float* ft    = (const float*)d_in[2];   // [16][3][11][11]
  const float* fn    = (const float*)d_in[3];   // [16][1][11][11]
  float* out = (float*)d_out;

  ushort_t* filtb = (ushort_t*)d_ws;
  ushort_t* prevb = filtb + FILTB_ELEMS;

  // Zero packed buffers (establishes zero padding) and the x2 accumulator.
  hipMemsetAsync(d_ws, 0, WS_BYTES, stream);
  hipMemsetAsync(out + X1_N, 0, (size_t)X2_N * sizeof(float), stream);

  feat_kernel<<<dim3(6, 96, 2), 64, 0, stream>>>(x, xprev, ft, fn, out, filtb, prevb);

  corr_kernel<<<dim3(16 * NCHUNK), 512, 0, stream>>>(filtb, prevb, out + X1_N);
}